// Round 1
// baseline (4037.173 us; speedup 1.0000x reference)
//
#include <hip/hip_runtime.h>
#include <hip/hip_bf16.h>

namespace {

constexpr int Md = 512, Cd = 256, Bd = 8, Td = 32;
constexpr float kLam = 0.05f, kRho = 0.9f, kDlr = 0.03f;
constexpr float kEps = 1e-12f, kLnEps = 1e-5f;

// ---- workspace layout (bytes) ----
constexpr size_t SZ_WC2  = (size_t)Cd * Cd * Md * 2;   // bf16 Wc2[c'][c][m]      = 64 MiB
constexpr size_t SZ_CU   = (size_t)Td * Bd * Cd * Md * 2; // bf16 CU[t][b][c][m]  = 64 MiB
constexpr size_t SZ_D    = (size_t)Bd * Cd * Md * 4;   // f32 D[b][c][m]          = 4 MiB
constexpr size_t SZ_S    = SZ_D;                       // f32 s_c[b][c][m]        = 4 MiB
constexpr size_t SZ_CST  = (size_t)Bd * Cd * 4;        // f32 c state
constexpr size_t SZ_RST  = (size_t)Bd * Md * 4;        // f32 r state
constexpr size_t SZ_WCUT = (size_t)Md * Cd * 4;        // f32 W_cu^T [d][c]
constexpr size_t SZ_WCCT = (size_t)Cd * Cd * 4;        // f32 W_cc^T [d][c]

constexpr size_t OFF_WC2  = 0;
constexpr size_t OFF_CU   = OFF_WC2 + SZ_WC2;
constexpr size_t OFF_D    = OFF_CU + SZ_CU;
constexpr size_t OFF_S    = OFF_D + SZ_D;
constexpr size_t OFF_CST  = OFF_S + SZ_S;
constexpr size_t OFF_RST  = OFF_CST + SZ_CST;
constexpr size_t OFF_AVAL = OFF_RST + SZ_RST;
constexpr size_t OFF_AIDX = OFF_AVAL + 256;
constexpr size_t OFF_GST  = OFF_AIDX + 256;
constexpr size_t OFF_WCUT = OFF_GST + 256;
constexpr size_t OFF_WCCT = OFF_WCUT + SZ_WCUT;

// ---- block-wide reductions (blockDim == 256) ----
__device__ __forceinline__ float block_reduce_sum(float v, float* sbuf) {
  const int tid = threadIdx.x;
  #pragma unroll
  for (int o = 32; o > 0; o >>= 1) v += __shfl_down(v, o, 64);
  __syncthreads();                       // protect sbuf reuse
  if ((tid & 63) == 0) sbuf[tid >> 6] = v;
  __syncthreads();
  return sbuf[0] + sbuf[1] + sbuf[2] + sbuf[3];
}

__device__ __forceinline__ float2 block_reduce_sum2(float a, float b, float* sbuf) {
  const int tid = threadIdx.x;
  #pragma unroll
  for (int o = 32; o > 0; o >>= 1) {
    a += __shfl_down(a, o, 64);
    b += __shfl_down(b, o, 64);
  }
  __syncthreads();
  if ((tid & 63) == 0) { sbuf[tid >> 6] = a; sbuf[4 + (tid >> 6)] = b; }
  __syncthreads();
  return make_float2(sbuf[0] + sbuf[1] + sbuf[2] + sbuf[3],
                     sbuf[4] + sbuf[5] + sbuf[6] + sbuf[7]);
}

// ---- init: D0 = column-normalized base dictionary (all batches), zero s_c and c ----
__global__ __launch_bounds__(256) void k_init(const float* __restrict__ base,
                                              float* __restrict__ D,
                                              float* __restrict__ S,
                                              float* __restrict__ cst) {
  __shared__ float red[8];
  const int tid = threadIdx.x;
  const int c = blockIdx.x;
  float b0 = base[(size_t)tid * Cd + c];
  float b1 = base[(size_t)(tid + 256) * Cd + c];
  float ss = block_reduce_sum(b0 * b0 + b1 * b1, red);
  float rinv = 1.0f / fmaxf(sqrtf(ss), kEps);
  #pragma unroll
  for (int bb = 0; bb < Bd; ++bb) {
    size_t off = ((size_t)(bb * Cd + c)) * Md;
    D[off + tid] = b0 * rinv;
    D[off + tid + 256] = b1 * rinv;
  }
  size_t s0 = (size_t)c * 4096;
  #pragma unroll
  for (int k = 0; k < 16; ++k) S[s0 + k * 256 + tid] = 0.0f;
  if (c < Bd) cst[c * Cd + tid] = 0.0f;
}

// ---- small transposes of W_cu (C,M) and W_cc (C,C) into [d][c] layout ----
__global__ __launch_bounds__(256) void k_transpose_small(const float* __restrict__ Wcu,
                                                         const float* __restrict__ Wcc,
                                                         float* __restrict__ WcuT,
                                                         float* __restrict__ WccT) {
  int g = blockIdx.x * 256 + threadIdx.x;
  if (g < Md * Cd) {
    int d = g >> 8, c = g & 255;
    WcuT[g] = Wcu[(size_t)c * Md + d];
  } else {
    int g2 = g - Md * Cd;
    int d = g2 >> 8, c = g2 & 255;
    WccT[g2] = Wcc[(size_t)c * Cd + d];
  }
}

// ---- build Wc2[c'][c][m] = W_cand_c[(m*C+c)][c'] as bf16 (tiled transpose) ----
__global__ __launch_bounds__(256) void k_build_wc2(const float* __restrict__ Wc,
                                                   __hip_bfloat16* __restrict__ Wc2) {
  __shared__ float tile[64][65];
  const int tid = threadIdx.x;
  const int bid = blockIdx.x;
  const int ct = bid & 3;
  const int mt = (bid >> 2) & 7;
  const int c = bid >> 5;
  const int c0p = ct * 64, m0 = mt * 64;
  const int x = tid & 63, y = tid >> 6;
  #pragma unroll
  for (int i = 0; i < 16; ++i) {
    int mm = m0 + y + i * 4;
    tile[y + i * 4][x] = Wc[((size_t)(mm * Cd + c)) * Cd + c0p + x];
  }
  __syncthreads();
  #pragma unroll
  for (int i = 0; i < 16; ++i) {
    int cp = c0p + y + i * 4;
    Wc2[((size_t)(cp * Cd + c)) * Md + m0 + x] = __float2bfloat16(tile[x][y + i * 4]);
  }
}

// ---- precompute CU[t][b][c][m] = u_t[b]·Wu_row(m*C+c) + b_u + b_c  (fp32 GEMM, bf16 out) ----
__global__ __launch_bounds__(256) void k_build_cu(const float* __restrict__ u,
                                                  const float* __restrict__ Wu,
                                                  const float* __restrict__ bu,
                                                  const float* __restrict__ bc,
                                                  __hip_bfloat16* __restrict__ CU) {
  __shared__ float Wl[32][65];   // [d][m], pad 65 -> conflict-free transpose-on-load
  __shared__ float Ul[32][257];  // [d][n]
  const int tid = threadIdx.x;
  const int c = blockIdx.x >> 3;
  const int m0 = (blockIdx.x & 7) * 64;
  const int ti = tid & 15, tj = tid >> 4;
  float acc[4][16];
  #pragma unroll
  for (int i = 0; i < 4; ++i)
    #pragma unroll
    for (int j = 0; j < 16; ++j) acc[i][j] = 0.0f;

  for (int ch = 0; ch < 16; ++ch) {
    const int d0 = ch * 32;
    #pragma unroll
    for (int k = 0; k < 8; ++k) {
      int e = tid + k * 256;
      int row = e >> 5, dd = e & 31;
      Wl[dd][row] = Wu[((size_t)((m0 + row) * Cd + c)) * Md + d0 + dd];
    }
    #pragma unroll
    for (int k = 0; k < 32; ++k) {
      int e = tid + k * 256;
      int n = e >> 5, dd = e & 31;
      int bb = n & 7, ts = n >> 3;
      Ul[dd][n] = u[(size_t)(bb * Td + ts) * Md + d0 + dd];
    }
    __syncthreads();
    #pragma unroll 8
    for (int d = 0; d < 32; ++d) {
      float w0 = Wl[d][ti * 4 + 0];
      float w1 = Wl[d][ti * 4 + 1];
      float w2 = Wl[d][ti * 4 + 2];
      float w3 = Wl[d][ti * 4 + 3];
      #pragma unroll
      for (int j = 0; j < 16; ++j) {
        float uv = Ul[d][tj * 16 + j];
        acc[0][j] = fmaf(w0, uv, acc[0][j]);
        acc[1][j] = fmaf(w1, uv, acc[1][j]);
        acc[2][j] = fmaf(w2, uv, acc[2][j]);
        acc[3][j] = fmaf(w3, uv, acc[3][j]);
      }
    }
    __syncthreads();
  }
  float biasv[4];
  #pragma unroll
  for (int i = 0; i < 4; ++i) {
    int m = m0 + ti * 4 + i;
    biasv[i] = bu[(size_t)m * Cd + c] + bc[(size_t)m * Cd + c];
  }
  struct alignas(8) BH4 { __hip_bfloat16 a, b, c2, d; };
  #pragma unroll
  for (int j = 0; j < 16; ++j) {
    int n = tj * 16 + j;
    BH4 pk;
    pk.a  = __float2bfloat16(acc[0][j] + biasv[0]);
    pk.b  = __float2bfloat16(acc[1][j] + biasv[1]);
    pk.c2 = __float2bfloat16(acc[2][j] + biasv[2]);
    pk.d  = __float2bfloat16(acc[3][j] + biasv[3]);
    *reinterpret_cast<BH4*>(&CU[((size_t)(n * Cd + c)) * Md + m0 + ti * 4]) = pk;
  }
}

// ---- per-step small kernel: LN, logits, top-8 shrink, c_t, u_hat/r/err, gate, zero z ----
__global__ __launch_bounds__(256) void k_step_small(
    const float* __restrict__ u, const float* __restrict__ valid,
    const float* __restrict__ WcuT, const float* __restrict__ WccT,
    const float* __restrict__ Wg, const float* __restrict__ bg,
    const float* __restrict__ lug, const float* __restrict__ lub,
    const float* __restrict__ lcg, const float* __restrict__ lcb,
    const float* __restrict__ D, float* __restrict__ cst,
    float* __restrict__ rst, float* __restrict__ aval_g, int* __restrict__ aidx_g,
    float* __restrict__ gst, float* __restrict__ out, int t) {
  __shared__ float lnu[512];
  __shared__ float lnc[256];
  __shared__ float score[256];
  __shared__ float sh[256];
  __shared__ float red[8];
  __shared__ float aval_s[8];
  __shared__ int aidx_s[8];
  const int tid = threadIdx.x;
  const int b = blockIdx.x;

  float cprev = cst[b * Cd + tid];
  float u0 = u[(size_t)(b * Td + t) * Md + tid];
  float u1 = u[(size_t)(b * Td + t) * Md + tid + 256];

  float mu = block_reduce_sum(u0 + u1, red) * (1.0f / 512.0f);
  float d0 = u0 - mu, d1 = u1 - mu;
  float var = block_reduce_sum(d0 * d0 + d1 * d1, red) * (1.0f / 512.0f);
  float rs = rsqrtf(var + kLnEps);
  lnu[tid] = d0 * rs * lug[tid] + lub[tid];
  lnu[tid + 256] = d1 * rs * lug[tid + 256] + lub[tid + 256];

  float muc = block_reduce_sum(cprev, red) * (1.0f / 256.0f);
  float dc = cprev - muc;
  float varc = block_reduce_sum(dc * dc, red) * (1.0f / 256.0f);
  lnc[tid] = dc * rsqrtf(varc + kLnEps) * lcg[tid] + lcb[tid];
  __syncthreads();

  // logits for column tid
  float acc = 0.0f;
  #pragma unroll 8
  for (int d = 0; d < Md; ++d) acc = fmaf(lnu[d], WcuT[d * Cd + tid], acc);
  #pragma unroll 8
  for (int d = 0; d < Cd; ++d) acc = fmaf(lnc[d], WccT[d * Cd + tid], acc);

  float sv = fmaxf(fabsf(acc) - kLam, 0.0f);
  float shv = (acc >= 0.0f) ? sv : -sv;
  sh[tid] = shv;
  score[tid] = sv;   // |shrunk|
  __syncthreads();

  // wave-0 top-8 (value desc, index asc tie-break)
  if (tid < 64) {
    float v4[4]; int i4[4];
    #pragma unroll
    for (int k = 0; k < 4; ++k) { i4[k] = tid * 4 + k; v4[k] = score[tid * 4 + k]; }
    for (int i = 0; i < 8; ++i) {
      float bv = v4[0]; int bi = i4[0];
      #pragma unroll
      for (int k = 1; k < 4; ++k)
        if (v4[k] > bv || (v4[k] == bv && i4[k] < bi)) { bv = v4[k]; bi = i4[k]; }
      #pragma unroll
      for (int o = 32; o > 0; o >>= 1) {
        float ov = __shfl_xor(bv, o, 64);
        int oi = __shfl_xor(bi, o, 64);
        if (ov > bv || (ov == bv && oi < bi)) { bv = ov; bi = oi; }
      }
      if (tid == 0) { aidx_s[i] = bi; aval_s[i] = sh[bi]; }
      if ((bi >> 2) == tid) v4[bi & 3] = -1.0f;
    }
  }
  __syncthreads();

  // c update (thread = column tid)
  float a_c = 0.0f;
  #pragma unroll
  for (int i = 0; i < 8; ++i) if (aidx_s[i] == tid) a_c = aval_s[i];
  float v = valid[b * Td + t];
  float cn = kRho * cprev + (1.0f - kRho) * a_c;
  float ct = v * cn + (1.0f - v) * cprev;
  cst[b * Cd + tid] = ct;
  if (tid < 8) { aval_g[b * 8 + tid] = aval_s[tid]; aidx_g[b * 8 + tid] = aidx_s[tid]; }

  // u_hat (8-sparse), r, err — D is pre-update here (before k_step_big runs)
  float uh0 = 0.0f, uh1 = 0.0f;
  #pragma unroll
  for (int i = 0; i < 8; ++i) {
    int ci = aidx_s[i]; float av = aval_s[i];
    const float* Drow = D + ((size_t)(b * Cd + ci)) * Md;
    uh0 += av * Drow[tid];
    uh1 += av * Drow[tid + 256];
  }
  float r0 = u0 - uh0, r1 = u1 - uh1;
  rst[b * Md + tid] = r0;
  rst[b * Md + tid + 256] = r1;
  float errss = block_reduce_sum(r0 * r0 + r1 * r1, red);
  float err = sqrtf(errss);

  // gate
  float gp = Wg[tid] * u0 + Wg[tid + 256] * u1 + Wg[512 + tid] * ct;
  float gsum = block_reduce_sum(gp, red);
  if (tid == 0) {
    gsum += Wg[768] * err + bg[0];
    gst[b] = 1.0f / (1.0f + expf(-gsum));
  }
  // zero this step's output slice (harness poisons d_out)
  out[(size_t)(b * Td + t) * Md + tid] = 0.0f;
  out[(size_t)(b * Td + t) * Md + tid + 256] = 0.0f;
}

// ---- per-step big kernel: s_c recursion, cand, 3 column norms, D update, z ----
__global__ __launch_bounds__(256) void k_step_big(
    const float* __restrict__ valid,
    const __hip_bfloat16* __restrict__ Wc2, const __hip_bfloat16* __restrict__ CU,
    float* __restrict__ D, float* __restrict__ S,
    const float* __restrict__ cst, const float* __restrict__ rst,
    const float* __restrict__ aval_g, const int* __restrict__ aidx_g,
    const float* __restrict__ gst, float* __restrict__ out, int t) {
  __shared__ float red[8];
  __shared__ float aval_s[8];
  __shared__ int aidx_s[8];
  const int tid = threadIdx.x;
  const int b = blockIdx.x >> 6;          // 512 blocks: 64 per batch
  const int c0 = (blockIdx.x & 63) * 4;   // 4 columns each

  if (tid < 8) { aval_s[tid] = aval_g[b * 8 + tid]; aidx_s[tid] = aidx_g[b * 8 + tid]; }
  __syncthreads();
  const float g = gst[b];
  const float v = valid[b * Td + t];
  const float r0 = rst[b * Md + tid];
  const float r1 = rst[b * Md + tid + 256];
  float z0 = 0.0f, z1 = 0.0f;

  for (int cc = 0; cc < 4; ++cc) {
    const int c = c0 + cc;
    float a_c = 0.0f;
    #pragma unroll
    for (int i = 0; i < 8; ++i) if (aidx_s[i] == c) a_c = aval_s[i];
    const float ctc = cst[b * Cd + c];
    const size_t dbase = ((size_t)(b * Cd + c)) * Md;
    const size_t cubase = ((size_t)((t * Bd + b) * Cd + c)) * Md;

    // s_c recursion with 8-sparse a gathered from Wc2 rows
    float w0 = 0.0f, w1 = 0.0f;
    #pragma unroll
    for (int i = 0; i < 8; ++i) {
      const __hip_bfloat16* wr = Wc2 + ((size_t)(aidx_s[i] * Cd + c)) * Md;
      float av = aval_s[i];
      w0 += av * __bfloat162float(wr[tid]);
      w1 += av * __bfloat162float(wr[tid + 256]);
    }
    float s0 = S[dbase + tid], s1 = S[dbase + tid + 256];
    float sn0 = v * (kRho * s0 + (1.0f - kRho) * w0) + (1.0f - v) * s0;
    float sn1 = v * (kRho * s1 + (1.0f - kRho) * w1) + (1.0f - v) * s1;
    S[dbase + tid] = sn0;
    S[dbase + tid + 256] = sn1;

    float cand0 = __bfloat162float(CU[cubase + tid]) + sn0;
    float cand1 = __bfloat162float(CU[cubase + tid + 256]) + sn1;
    float dold0 = D[dbase + tid], dold1 = D[dbase + tid + 256];
    float dl0 = fmaf(kDlr * a_c, r0, dold0);
    float dl1 = fmaf(kDlr * a_c, r1, dold1);

    float2 ss = block_reduce_sum2(cand0 * cand0 + cand1 * cand1,
                                  dl0 * dl0 + dl1 * dl1, red);
    float rinv_c = 1.0f / fmaxf(sqrtf(ss.x), kEps);
    float rinv_d = 1.0f / fmaxf(sqrtf(ss.y), kEps);

    float e0 = (1.0f - g) * dl0 * rinv_d + g * cand0 * rinv_c;
    float e1 = (1.0f - g) * dl1 * rinv_d + g * cand1 * rinv_c;
    float sse = block_reduce_sum(e0 * e0 + e1 * e1, red);
    float rinv_e = 1.0f / fmaxf(sqrtf(sse), kEps);

    float dn0 = v * (e0 * rinv_e) + (1.0f - v) * dold0;
    float dn1 = v * (e1 * rinv_e) + (1.0f - v) * dold1;
    D[dbase + tid] = dn0;
    D[dbase + tid + 256] = dn1;
    z0 = fmaf(dn0, ctc, z0);
    z1 = fmaf(dn1, ctc, z1);
  }
  atomicAdd(&out[(size_t)(b * Td + t) * Md + tid], z0);
  atomicAdd(&out[(size_t)(b * Td + t) * Md + tid + 256], z1);
}

}  // namespace

extern "C" void kernel_launch(void* const* d_in, const int* in_sizes, int n_in,
                              void* d_out, int out_size, void* d_ws, size_t ws_size,
                              hipStream_t stream) {
  (void)in_sizes; (void)n_in; (void)out_size; (void)ws_size;
  const float* u     = (const float*)d_in[0];
  const float* valid = (const float*)d_in[1];
  const float* base  = (const float*)d_in[2];
  const float* Wcu   = (const float*)d_in[3];
  const float* Wcc   = (const float*)d_in[4];
  const float* Wu    = (const float*)d_in[5];
  const float* bu    = (const float*)d_in[6];
  const float* Wc    = (const float*)d_in[7];
  const float* bc    = (const float*)d_in[8];
  const float* Wg    = (const float*)d_in[9];
  const float* bg    = (const float*)d_in[10];
  const float* lug   = (const float*)d_in[11];
  const float* lub   = (const float*)d_in[12];
  const float* lcg   = (const float*)d_in[13];
  const float* lcb   = (const float*)d_in[14];
  float* out = (float*)d_out;
  char* ws = (char*)d_ws;

  __hip_bfloat16* Wc2 = (__hip_bfloat16*)(ws + OFF_WC2);
  __hip_bfloat16* CU  = (__hip_bfloat16*)(ws + OFF_CU);
  float* D    = (float*)(ws + OFF_D);
  float* S    = (float*)(ws + OFF_S);
  float* cst  = (float*)(ws + OFF_CST);
  float* rst  = (float*)(ws + OFF_RST);
  float* aval = (float*)(ws + OFF_AVAL);
  int*   aidx = (int*)(ws + OFF_AIDX);
  float* gst  = (float*)(ws + OFF_GST);
  float* WcuT = (float*)(ws + OFF_WCUT);
  float* WccT = (float*)(ws + OFF_WCCT);

  hipLaunchKernelGGL(k_init, dim3(Cd), dim3(256), 0, stream, base, D, S, cst);
  hipLaunchKernelGGL(k_transpose_small, dim3(768), dim3(256), 0, stream,
                     Wcu, Wcc, WcuT, WccT);
  hipLaunchKernelGGL(k_build_wc2, dim3(8192), dim3(256), 0, stream, Wc, Wc2);
  hipLaunchKernelGGL(k_build_cu, dim3(2048), dim3(256), 0, stream, u, Wu, bu, bc, CU);

  for (int t = 0; t < Td; ++t) {
    hipLaunchKernelGGL(k_step_small, dim3(Bd), dim3(256), 0, stream,
                       u, valid, WcuT, WccT, Wg, bg, lug, lub, lcg, lcb,
                       D, cst, rst, aval, aidx, gst, out, t);
    hipLaunchKernelGGL(k_step_big, dim3(512), dim3(256), 0, stream,
                       valid, Wc2, CU, D, S, cst, rst, aval, aidx, gst, out, t);
  }
}

// Round 2
// 1456.449 us; speedup vs baseline: 2.7719x; 2.7719x over previous
//
#include <hip/hip_runtime.h>
#include <hip/hip_bf16.h>

namespace {

constexpr int Md = 512, Cd = 256, Bd = 8, Td = 32;
constexpr float kLam = 0.05f, kRho = 0.9f, kDlr = 0.03f;
constexpr float kEps = 1e-12f, kLnEps = 1e-5f;

typedef __attribute__((ext_vector_type(8))) short short8;
typedef __attribute__((ext_vector_type(4))) float float4v;

// ---- workspace layout (bytes) ----
constexpr size_t SZ_WC2  = (size_t)Cd * Cd * Md * 2;      // bf16 Wc2[c'][c][m]
constexpr size_t SZ_CU   = (size_t)Td * Bd * Cd * Md * 2; // bf16 CU[t][b][c][m]
constexpr size_t SZ_D    = (size_t)Bd * Cd * Md * 4;      // f32 D[b][c][m]
constexpr size_t SZ_S    = SZ_D;                          // f32 s_c[b][c][m]
constexpr size_t SZ_CST  = (size_t)Bd * Cd * 4;
constexpr size_t SZ_RST  = (size_t)Bd * Md * 4;
constexpr size_t SZ_WCUT = (size_t)Md * Cd * 4;
constexpr size_t SZ_WCCT = (size_t)Cd * Cd * 4;
constexpr size_t SZ_UB   = (size_t)Td * Bd * Md * 2;      // bf16 Ub[n][d], n=t*8+b
constexpr size_t SZ_ZP   = (size_t)Bd * 32 * Md * 4;      // f32 zpart[b][32][m]

constexpr size_t OFF_WC2  = 0;
constexpr size_t OFF_CU   = OFF_WC2 + SZ_WC2;
constexpr size_t OFF_D    = OFF_CU + SZ_CU;
constexpr size_t OFF_S    = OFF_D + SZ_D;
constexpr size_t OFF_CST  = OFF_S + SZ_S;
constexpr size_t OFF_RST  = OFF_CST + SZ_CST;
constexpr size_t OFF_AVAL = OFF_RST + SZ_RST;
constexpr size_t OFF_AIDX = OFF_AVAL + 256;
constexpr size_t OFF_GST  = OFF_AIDX + 256;
constexpr size_t OFF_WCUT = OFF_GST + 256;
constexpr size_t OFF_WCCT = OFF_WCUT + SZ_WCUT;
constexpr size_t OFF_UB   = OFF_WCCT + SZ_WCCT;
constexpr size_t OFF_ZP   = OFF_UB + SZ_UB;

__device__ __forceinline__ unsigned short f2bf(float x) {
  __hip_bfloat16 h = __float2bfloat16(x);
  return *reinterpret_cast<unsigned short*>(&h);
}

// ---- 256-thread block reductions ----
__device__ __forceinline__ float block_reduce_sum(float v, float* sbuf) {
  const int tid = threadIdx.x;
  #pragma unroll
  for (int o = 32; o > 0; o >>= 1) v += __shfl_down(v, o, 64);
  __syncthreads();
  if ((tid & 63) == 0) sbuf[tid >> 6] = v;
  __syncthreads();
  return sbuf[0] + sbuf[1] + sbuf[2] + sbuf[3];
}

__device__ __forceinline__ float2 block_reduce_sum2(float a, float b, float* sbuf) {
  const int tid = threadIdx.x;
  #pragma unroll
  for (int o = 32; o > 0; o >>= 1) {
    a += __shfl_down(a, o, 64);
    b += __shfl_down(b, o, 64);
  }
  __syncthreads();
  if ((tid & 63) == 0) { sbuf[tid >> 6] = a; sbuf[4 + (tid >> 6)] = b; }
  __syncthreads();
  return make_float2(sbuf[0] + sbuf[1] + sbuf[2] + sbuf[3],
                     sbuf[4] + sbuf[5] + sbuf[6] + sbuf[7]);
}

// ---- 1024-thread block reductions ----
__device__ __forceinline__ void reduce4_1024(float& a, float& b, float& c, float& d,
                                             float* red) {
  const int tid = threadIdx.x;
  #pragma unroll
  for (int o = 32; o > 0; o >>= 1) {
    a += __shfl_down(a, o, 64); b += __shfl_down(b, o, 64);
    c += __shfl_down(c, o, 64); d += __shfl_down(d, o, 64);
  }
  __syncthreads();
  if ((tid & 63) == 0) {
    int wv = tid >> 6;
    red[wv * 4] = a; red[wv * 4 + 1] = b; red[wv * 4 + 2] = c; red[wv * 4 + 3] = d;
  }
  __syncthreads();
  float A = 0, B = 0, C = 0, D2 = 0;
  #pragma unroll
  for (int g = 0; g < 16; ++g) {
    A += red[g * 4]; B += red[g * 4 + 1]; C += red[g * 4 + 2]; D2 += red[g * 4 + 3];
  }
  a = A; b = B; c = C; d = D2;
}

__device__ __forceinline__ void reduce2_1024(float& a, float& b, float* red) {
  const int tid = threadIdx.x;
  #pragma unroll
  for (int o = 32; o > 0; o >>= 1) {
    a += __shfl_down(a, o, 64); b += __shfl_down(b, o, 64);
  }
  __syncthreads();
  if ((tid & 63) == 0) { int wv = tid >> 6; red[wv * 2] = a; red[wv * 2 + 1] = b; }
  __syncthreads();
  float A = 0, B = 0;
  #pragma unroll
  for (int g = 0; g < 16; ++g) { A += red[g * 2]; B += red[g * 2 + 1]; }
  a = A; b = B;
}

// ---- init: D0 = column-normalized base dictionary, zero s_c and c ----
__global__ __launch_bounds__(256) void k_init(const float* __restrict__ base,
                                              float* __restrict__ D,
                                              float* __restrict__ S,
                                              float* __restrict__ cst) {
  __shared__ float red[8];
  const int tid = threadIdx.x;
  const int c = blockIdx.x;
  float b0 = base[(size_t)tid * Cd + c];
  float b1 = base[(size_t)(tid + 256) * Cd + c];
  float ss = block_reduce_sum(b0 * b0 + b1 * b1, red);
  float rinv = 1.0f / fmaxf(sqrtf(ss), kEps);
  #pragma unroll
  for (int bb = 0; bb < Bd; ++bb) {
    size_t off = ((size_t)(bb * Cd + c)) * Md;
    D[off + tid] = b0 * rinv;
    D[off + tid + 256] = b1 * rinv;
  }
  size_t s0 = (size_t)c * 4096;
  #pragma unroll
  for (int k = 0; k < 16; ++k) S[s0 + k * 256 + tid] = 0.0f;
  if (c < Bd) cst[c * Cd + tid] = 0.0f;
}

// ---- transposes of W_cu (C,M) and W_cc (C,C) into [d][c] layout ----
__global__ __launch_bounds__(256) void k_transpose_small(const float* __restrict__ Wcu,
                                                         const float* __restrict__ Wcc,
                                                         float* __restrict__ WcuT,
                                                         float* __restrict__ WccT) {
  int g = blockIdx.x * 256 + threadIdx.x;
  if (g < Md * Cd) {
    int d = g >> 8, c = g & 255;
    WcuT[g] = Wcu[(size_t)c * Md + d];
  } else {
    int g2 = g - Md * Cd;
    int d = g2 >> 8, c = g2 & 255;
    WccT[g2] = Wcc[(size_t)c * Cd + d];
  }
}

// ---- build Wc2[c'][c][m] = W_cand_c[(m*C+c)][c'] as bf16 ----
__global__ __launch_bounds__(256) void k_build_wc2(const float* __restrict__ Wc,
                                                   __hip_bfloat16* __restrict__ Wc2) {
  __shared__ float tile[64][65];
  const int tid = threadIdx.x;
  const int bid = blockIdx.x;
  const int ct = bid & 3;
  const int mt = (bid >> 2) & 7;
  const int c = bid >> 5;
  const int c0p = ct * 64, m0 = mt * 64;
  const int x = tid & 63, y = tid >> 6;
  #pragma unroll
  for (int i = 0; i < 16; ++i) {
    int mm = m0 + y + i * 4;
    tile[y + i * 4][x] = Wc[((size_t)(mm * Cd + c)) * Cd + c0p + x];
  }
  __syncthreads();
  #pragma unroll
  for (int i = 0; i < 16; ++i) {
    int cp = c0p + y + i * 4;
    Wc2[((size_t)(cp * Cd + c)) * Md + m0 + x] = __float2bfloat16(tile[x][y + i * 4]);
  }
}

// ---- convert u -> bf16 Ub[n][d], n = t*8+b ----
__global__ __launch_bounds__(256) void k_prep_u(const float* __restrict__ u,
                                                __hip_bfloat16* __restrict__ Ub) {
  const int n = blockIdx.x;
  const int t = n >> 3, b = n & 7;
  const int tid = threadIdx.x;
  const float* src = u + ((size_t)(b * Td + t)) * Md;
  __hip_bfloat16* dst = Ub + (size_t)n * Md;
  dst[tid] = __float2bfloat16(src[tid]);
  dst[tid + 256] = __float2bfloat16(src[tid + 256]);
}

// ---- MFMA precompute: CU[n][c][m] = Ub[n]·Wu_row(m*C+c) + b_u + b_c ----
// grid 2048 = c(256) x mt(8); block 256 thr = 4 waves; tile 64 m x 256 tokens.
__global__ __launch_bounds__(256) void k_build_cu(const float* __restrict__ Wu,
                                                  const float* __restrict__ bu,
                                                  const float* __restrict__ bc,
                                                  const __hip_bfloat16* __restrict__ Ub,
                                                  __hip_bfloat16* __restrict__ CU) {
  __shared__ unsigned short smem[256 * 72];  // Bs: stride 40; Ct: stride 72
  const int tid = threadIdx.x;
  const int c = blockIdx.x >> 3;
  const int mt = blockIdx.x & 7;
  const int w = tid >> 6;
  const int lane = tid & 63;
  const int l15 = lane & 15;
  const int quad = lane >> 4;

  float4v acc[16];
  #pragma unroll
  for (int j = 0; j < 16; ++j) acc[j] = (float4v){0.f, 0.f, 0.f, 0.f};

  const int mrow = mt * 64 + w * 16 + l15;  // this lane's A row (m)
  const float* Arow = Wu + ((size_t)mrow * Cd + c) * Md;
  const unsigned short* ubp = (const unsigned short*)Ub + (size_t)tid * Md;

  for (int ch = 0; ch < 16; ++ch) {
    const int d0 = ch * 32;
    // stage B chunk: token tid, 32 bf16
    short8 s0 = *(const short8*)(ubp + d0);
    short8 s1 = *(const short8*)(ubp + d0 + 8);
    short8 s2 = *(const short8*)(ubp + d0 + 16);
    short8 s3 = *(const short8*)(ubp + d0 + 24);
    __syncthreads();  // previous iteration's ds_reads done
    *(short8*)&smem[tid * 40 + 0]  = s0;
    *(short8*)&smem[tid * 40 + 8]  = s1;
    *(short8*)&smem[tid * 40 + 16] = s2;
    *(short8*)&smem[tid * 40 + 24] = s3;
    // A fragment direct from HBM (fp32 -> bf16)
    float4 a0 = *(const float4*)(Arow + d0 + quad * 8);
    float4 a1 = *(const float4*)(Arow + d0 + quad * 8 + 4);
    short8 af;
    af[0] = (short)f2bf(a0.x); af[1] = (short)f2bf(a0.y);
    af[2] = (short)f2bf(a0.z); af[3] = (short)f2bf(a0.w);
    af[4] = (short)f2bf(a1.x); af[5] = (short)f2bf(a1.y);
    af[6] = (short)f2bf(a1.z); af[7] = (short)f2bf(a1.w);
    __syncthreads();  // Bs visible
    #pragma unroll
    for (int j = 0; j < 16; ++j) {
      short8 bf = *(const short8*)&smem[(j * 16 + l15) * 40 + quad * 8];
      acc[j] = __builtin_amdgcn_mfma_f32_16x16x32_bf16(af, bf, acc[j], 0, 0, 0);
    }
  }

  // epilogue: bias, pack, LDS transpose, coalesced store
  float bias[4];
  #pragma unroll
  for (int r2 = 0; r2 < 4; ++r2) {
    int m = mt * 64 + w * 16 + quad * 4 + r2;
    bias[r2] = bu[(size_t)m * Cd + c] + bc[(size_t)m * Cd + c];
  }
  __syncthreads();  // last ds_reads done before smem reuse
  #pragma unroll
  for (int j = 0; j < 16; ++j) {
    int tok = j * 16 + l15;
    int mlb = w * 16 + quad * 4;
    uint2 pk;
    pk.x = (unsigned)f2bf(acc[j][0] + bias[0]) |
           ((unsigned)f2bf(acc[j][1] + bias[1]) << 16);
    pk.y = (unsigned)f2bf(acc[j][2] + bias[2]) |
           ((unsigned)f2bf(acc[j][3] + bias[3]) << 16);
    *(uint2*)&smem[tok * 72 + mlb] = pk;
  }
  __syncthreads();
  #pragma unroll
  for (int rr = 0; rr < 8; ++rr) {
    int tok = (tid >> 3) + rr * 32;
    int ml0 = (tid & 7) * 8;
    short8 vv = *(const short8*)&smem[tok * 72 + ml0];
    *(short8*)((unsigned short*)CU + ((size_t)tok * Cd + c) * Md + mt * 64 + ml0) = vv;
  }
}

// ---- per-step small kernel (1024 threads, 8 blocks = one per batch) ----
__global__ __launch_bounds__(1024) void k_step_small(
    const float* __restrict__ u, const float* __restrict__ valid,
    const float* __restrict__ WcuT, const float* __restrict__ WccT,
    const float* __restrict__ Wg, const float* __restrict__ bg,
    const float* __restrict__ lug, const float* __restrict__ lub,
    const float* __restrict__ lcg, const float* __restrict__ lcb,
    const float* __restrict__ D, float* __restrict__ cst,
    float* __restrict__ rst, float* __restrict__ aval_g, int* __restrict__ aidx_g,
    float* __restrict__ gst, float* __restrict__ zpart, float* __restrict__ out,
    int t) {
  __shared__ float lnu_s[512];
  __shared__ float lnc_s[256];
  __shared__ float us[512];
  __shared__ float lp[4][256];
  __shared__ float sc_s[256];
  __shared__ float sh_s[256];
  __shared__ float cts[256];
  __shared__ float red[64];
  __shared__ float aval_s[8];
  __shared__ int aidx_s[8];
  const int tid = threadIdx.x;
  const int b = blockIdx.x;

  // P0: LN stats for u_t and c_prev in one reduction round
  float u0 = 0.0f, cp = 0.0f;
  if (tid < 512) { u0 = u[((size_t)(b * Td + t)) * Md + tid]; us[tid] = u0; }
  else if (tid < 768) cp = cst[b * Cd + (tid - 512)];
  float s1 = u0, s2 = u0 * u0, s3 = cp, s4 = cp * cp;
  reduce4_1024(s1, s2, s3, s4, red);
  float mu = s1 * (1.0f / 512.0f);
  float var = s2 * (1.0f / 512.0f) - mu * mu;
  float rsu = rsqrtf(var + kLnEps);
  float muc = s3 * (1.0f / 256.0f);
  float varc = s4 * (1.0f / 256.0f) - muc * muc;
  float rsc = rsqrtf(varc + kLnEps);
  if (tid < 512) lnu_s[tid] = (u0 - mu) * rsu * lug[tid] + lub[tid];
  else if (tid < 768) {
    int c2 = tid - 512;
    lnc_s[c2] = (cp - muc) * rsc * lcg[c2] + lcb[c2];
  }
  __syncthreads();

  // P1: logits, 4 threads per column
  {
    const int c2 = tid & 255, q = tid >> 8;
    float acc = 0.0f;
    const float* wp = WcuT + (size_t)(q * 128) * Cd + c2;
    #pragma unroll 8
    for (int i = 0; i < 128; ++i) acc = fmaf(lnu_s[q * 128 + i], wp[(size_t)i * Cd], acc);
    const float* wp2 = WccT + (size_t)(q * 64) * Cd + c2;
    #pragma unroll 8
    for (int i = 0; i < 64; ++i) acc = fmaf(lnc_s[q * 64 + i], wp2[(size_t)i * Cd], acc);
    lp[q][c2] = acc;
  }
  __syncthreads();
  if (tid < 256) {
    float lg = lp[0][tid] + lp[1][tid] + lp[2][tid] + lp[3][tid];
    float sv = fmaxf(fabsf(lg) - kLam, 0.0f);
    sh_s[tid] = (lg >= 0.0f) ? sv : -sv;
    sc_s[tid] = sv;
  }
  __syncthreads();

  // P3: wave-0 top-8 (value desc, index asc tie-break)
  if (tid < 64) {
    float v4[4]; int i4[4];
    #pragma unroll
    for (int k = 0; k < 4; ++k) { i4[k] = tid * 4 + k; v4[k] = sc_s[tid * 4 + k]; }
    for (int i = 0; i < 8; ++i) {
      float bv = v4[0]; int bi = i4[0];
      #pragma unroll
      for (int k = 1; k < 4; ++k)
        if (v4[k] > bv || (v4[k] == bv && i4[k] < bi)) { bv = v4[k]; bi = i4[k]; }
      #pragma unroll
      for (int o = 32; o > 0; o >>= 1) {
        float ov = __shfl_xor(bv, o, 64);
        int oi = __shfl_xor(bi, o, 64);
        if (ov > bv || (ov == bv && oi < bi)) { bv = ov; bi = oi; }
      }
      if (tid == 0) { aidx_s[i] = bi; aval_s[i] = sh_s[bi]; }
      if ((bi >> 2) == tid) v4[bi & 3] = -1.0f;
    }
  }
  __syncthreads();

  // P4: c update
  const float v = valid[b * Td + t];
  if (tid < 256) {
    float a_c = 0.0f;
    #pragma unroll
    for (int i = 0; i < 8; ++i) if (aidx_s[i] == tid) a_c = aval_s[i];
    float cprev = cst[b * Cd + tid];
    float cn = kRho * cprev + (1.0f - kRho) * a_c;
    float ct = v * cn + (1.0f - v) * cprev;
    cst[b * Cd + tid] = ct;
    cts[tid] = ct;
  }
  if (tid < 8) { aval_g[b * 8 + tid] = aval_s[tid]; aidx_g[b * 8 + tid] = aidx_s[tid]; }
  __syncthreads();

  // P5: u_hat, r, err, gate
  float e2 = 0.0f, gp = 0.0f;
  if (tid < 512) {
    float uh = 0.0f;
    #pragma unroll
    for (int i = 0; i < 8; ++i)
      uh += aval_s[i] * D[((size_t)(b * Cd + aidx_s[i])) * Md + tid];
    float r = us[tid] - uh;
    rst[b * Md + tid] = r;
    e2 = r * r;
    gp = Wg[tid] * us[tid];
  } else if (tid < 768) {
    int c2 = tid - 512;
    gp = Wg[512 + c2] * cts[c2];
  }
  reduce2_1024(e2, gp, red);
  if (tid == 0) {
    float err = sqrtf(e2);
    float gg = gp + Wg[768] * err + bg[0];
    gst[b] = 1.0f / (1.0f + expf(-gg));
  }

  // P6: finalize z for step t-1 from zpart, then zero zpart for this step
  if (t > 0 && tid < 512) {
    float s = 0.0f;
    #pragma unroll
    for (int g2 = 0; g2 < 32; ++g2) s += zpart[((size_t)(b * 32 + g2)) * Md + tid];
    out[((size_t)(b * Td + (t - 1))) * Md + tid] = s;
  }
  __syncthreads();
  #pragma unroll
  for (int k2 = 0; k2 < 16; ++k2)
    zpart[(size_t)b * 16384 + k2 * 1024 + tid] = 0.0f;
}

// ---- per-step big kernel: 2048 blocks = (b, c); dictionary update + z partial ----
__global__ __launch_bounds__(256) void k_step_big(
    const float* __restrict__ valid,
    const __hip_bfloat16* __restrict__ Wc2, const __hip_bfloat16* __restrict__ CU,
    float* __restrict__ D, float* __restrict__ S,
    const float* __restrict__ cst, const float* __restrict__ rst,
    const float* __restrict__ aval_g, const int* __restrict__ aidx_g,
    const float* __restrict__ gst, float* __restrict__ zpart, int t) {
  __shared__ float red[8];
  __shared__ float aval_s[8];
  __shared__ int aidx_s[8];
  const int tid = threadIdx.x;
  const int b = blockIdx.x >> 8;
  const int c = blockIdx.x & 255;

  if (tid < 8) { aval_s[tid] = aval_g[b * 8 + tid]; aidx_s[tid] = aidx_g[b * 8 + tid]; }
  __syncthreads();
  const float g = gst[b];
  const float v = valid[b * Td + t];
  const float r0 = rst[b * Md + tid];
  const float r1 = rst[b * Md + tid + 256];

  float a_c = 0.0f;
  #pragma unroll
  for (int i = 0; i < 8; ++i) if (aidx_s[i] == c) a_c = aval_s[i];
  const float ctc = cst[b * Cd + c];
  const size_t dbase = ((size_t)(b * Cd + c)) * Md;
  const size_t cubase = ((size_t)((t * Bd + b) * Cd + c)) * Md;

  float w0 = 0.0f, w1 = 0.0f;
  #pragma unroll
  for (int i = 0; i < 8; ++i) {
    const __hip_bfloat16* wr = Wc2 + ((size_t)(aidx_s[i] * Cd + c)) * Md;
    float av = aval_s[i];
    w0 += av * __bfloat162float(wr[tid]);
    w1 += av * __bfloat162float(wr[tid + 256]);
  }
  float s0 = S[dbase + tid], s1 = S[dbase + tid + 256];
  float sn0 = v * (kRho * s0 + (1.0f - kRho) * w0) + (1.0f - v) * s0;
  float sn1 = v * (kRho * s1 + (1.0f - kRho) * w1) + (1.0f - v) * s1;
  S[dbase + tid] = sn0;
  S[dbase + tid + 256] = sn1;

  float cand0 = __bfloat162float(CU[cubase + tid]) + sn0;
  float cand1 = __bfloat162float(CU[cubase + tid + 256]) + sn1;
  float dold0 = D[dbase + tid], dold1 = D[dbase + tid + 256];
  float dl0 = fmaf(kDlr * a_c, r0, dold0);
  float dl1 = fmaf(kDlr * a_c, r1, dold1);

  float2 ss = block_reduce_sum2(cand0 * cand0 + cand1 * cand1,
                                dl0 * dl0 + dl1 * dl1, red);
  float rinv_c = 1.0f / fmaxf(sqrtf(ss.x), kEps);
  float rinv_d = 1.0f / fmaxf(sqrtf(ss.y), kEps);

  float e0 = (1.0f - g) * dl0 * rinv_d + g * cand0 * rinv_c;
  float e1 = (1.0f - g) * dl1 * rinv_d + g * cand1 * rinv_c;
  float sse = block_reduce_sum(e0 * e0 + e1 * e1, red);
  float rinv_e = 1.0f / fmaxf(sqrtf(sse), kEps);

  float dn0 = v * (e0 * rinv_e) + (1.0f - v) * dold0;
  float dn1 = v * (e1 * rinv_e) + (1.0f - v) * dold1;
  D[dbase + tid] = dn0;
  D[dbase + tid + 256] = dn1;

  float* zp = zpart + ((size_t)(b * 32 + (c >> 3))) * Md;
  atomicAdd(&zp[tid], dn0 * ctc);
  atomicAdd(&zp[tid + 256], dn1 * ctc);
}

// ---- final: z for t = T-1 ----
__global__ __launch_bounds__(512) void k_final(const float* __restrict__ zpart,
                                               float* __restrict__ out) {
  const int b = blockIdx.x;
  const int m = threadIdx.x;
  float s = 0.0f;
  #pragma unroll
  for (int g2 = 0; g2 < 32; ++g2) s += zpart[((size_t)(b * 32 + g2)) * Md + m];
  out[((size_t)(b * Td + (Td - 1))) * Md + m] = s;
}

}  // namespace

extern "C" void kernel_launch(void* const* d_in, const int* in_sizes, int n_in,
                              void* d_out, int out_size, void* d_ws, size_t ws_size,
                              hipStream_t stream) {
  (void)in_sizes; (void)n_in; (void)out_size; (void)ws_size;
  const float* u     = (const float*)d_in[0];
  const float* valid = (const float*)d_in[1];
  const float* base  = (const float*)d_in[2];
  const float* Wcu   = (const float*)d_in[3];
  const float* Wcc   = (const float*)d_in[4];
  const float* Wu    = (const float*)d_in[5];
  const float* bu    = (const float*)d_in[6];
  const float* Wc    = (const float*)d_in[7];
  const float* bc    = (const float*)d_in[8];
  const float* Wg    = (const float*)d_in[9];
  const float* bg    = (const float*)d_in[10];
  const float* lug   = (const float*)d_in[11];
  const float* lub   = (const float*)d_in[12];
  const float* lcg   = (const float*)d_in[13];
  const float* lcb   = (const float*)d_in[14];
  float* out = (float*)d_out;
  char* ws = (char*)d_ws;

  __hip_bfloat16* Wc2 = (__hip_bfloat16*)(ws + OFF_WC2);
  __hip_bfloat16* CU  = (__hip_bfloat16*)(ws + OFF_CU);
  float* D    = (float*)(ws + OFF_D);
  float* S    = (float*)(ws + OFF_S);
  float* cst  = (float*)(ws + OFF_CST);
  float* rst  = (float*)(ws + OFF_RST);
  float* aval = (float*)(ws + OFF_AVAL);
  int*   aidx = (int*)(ws + OFF_AIDX);
  float* gst  = (float*)(ws + OFF_GST);
  float* WcuT = (float*)(ws + OFF_WCUT);
  float* WccT = (float*)(ws + OFF_WCCT);
  __hip_bfloat16* Ub = (__hip_bfloat16*)(ws + OFF_UB);
  float* zpart = (float*)(ws + OFF_ZP);

  hipLaunchKernelGGL(k_init, dim3(Cd), dim3(256), 0, stream, base, D, S, cst);
  hipLaunchKernelGGL(k_transpose_small, dim3(768), dim3(256), 0, stream,
                     Wcu, Wcc, WcuT, WccT);
  hipLaunchKernelGGL(k_build_wc2, dim3(8192), dim3(256), 0, stream, Wc, Wc2);
  hipLaunchKernelGGL(k_prep_u, dim3(256), dim3(256), 0, stream, u, Ub);
  hipLaunchKernelGGL(k_build_cu, dim3(2048), dim3(256), 0, stream, Wu, bu, bc, Ub, CU);

  for (int t = 0; t < Td; ++t) {
    hipLaunchKernelGGL(k_step_small, dim3(Bd), dim3(1024), 0, stream,
                       u, valid, WcuT, WccT, Wg, bg, lug, lub, lcg, lcb,
                       D, cst, rst, aval, aidx, gst, zpart, out, t);
    hipLaunchKernelGGL(k_step_big, dim3(2048), dim3(256), 0, stream,
                       valid, Wc2, CU, D, S, cst, rst, aval, aidx, gst, zpart, t);
  }
  hipLaunchKernelGGL(k_final, dim3(Bd), dim3(512), 0, stream, zpart, out);
}